// Round 1
// baseline (231.041 us; speedup 1.0000x reference)
//
#include <hip/hip_runtime.h>

#define B_ 16
#define C_ 128
#define D_ 256

// K1: P[row,k] = sum_d h[row,d]*W1[d,k]   (row = b*C+u, flat 2048 rows)
//     Q[row,k] = sum_d h[row,d]*W1[D+d,k] + b1[k]
__global__ __launch_bounds__(256) void k1_pq(const float* __restrict__ h,
                                             const float* __restrict__ W1,
                                             const float* __restrict__ b1,
                                             float* __restrict__ P,
                                             float* __restrict__ Q) {
  const int tid = threadIdx.x;
  const int col = blockIdx.x * 128 + (tid & 127);
  const int rbase = (tid >> 7) * 8;
  const int row0 = blockIdx.y * 16;
  __shared__ float hs[16][D_];
#pragma unroll
  for (int r = 0; r < 16; ++r) hs[r][tid] = h[(row0 + r) * D_ + tid];
  __syncthreads();
  float accP[8], accQ[8];
#pragma unroll
  for (int r = 0; r < 8; ++r) { accP[r] = 0.f; accQ[r] = 0.f; }
#pragma unroll 4
  for (int d = 0; d < D_; ++d) {
    const float wt = W1[d * D_ + col];
    const float wb = W1[(D_ + d) * D_ + col];
#pragma unroll
    for (int r = 0; r < 8; ++r) {
      accP[r] = fmaf(hs[rbase + r][d], wt, accP[r]);
      accQ[r] = fmaf(hs[rbase + r][d], wb, accQ[r]);
    }
  }
  const float bb = b1[col];
#pragma unroll
  for (int r = 0; r < 8; ++r) {
    P[(row0 + rbase + r) * D_ + col] = accP[r];
    Q[(row0 + rbase + r) * D_ + col] = accQ[r] + bb;
  }
}

// K2: SA_T[b,v,u] = sigmoid( sum_k relu(P[b,u,k]+Q[b,v,k]) * W2[k] + b2 ) * Aa[u,v]
__global__ __launch_bounds__(256) void k2_s(const float* __restrict__ P,
                                            const float* __restrict__ Q,
                                            const float* __restrict__ W2,
                                            const float* __restrict__ b2,
                                            const float* __restrict__ Aa,
                                            float* __restrict__ SA) {
  const int b = blockIdx.z;
  const int u0 = blockIdx.x * 32;
  const int v0 = blockIdx.y * 32;
  const int tid = threadIdx.x;
  const int tx = tid & 15;   // -> v pair
  const int ty = tid >> 4;   // -> u pair
  __shared__ float Pl[32][257];   // stride 257: distinct banks per row
  __shared__ float Ql[32][257];
  __shared__ float W2l[D_];
  const float* Pb = P + (b * C_ + u0) * D_;
  const float* Qb = Q + (b * C_ + v0) * D_;
#pragma unroll
  for (int r = 0; r < 32; ++r) {
    Pl[r][tid] = Pb[r * D_ + tid];
    Ql[r][tid] = Qb[r * D_ + tid];
  }
  W2l[tid] = W2[tid];
  __syncthreads();
  const int uu0 = 2 * ty, uu1 = uu0 + 1;
  const int vv0 = 2 * tx, vv1 = vv0 + 1;
  float a00 = 0.f, a01 = 0.f, a10 = 0.f, a11 = 0.f;
#pragma unroll 4
  for (int k = 0; k < D_; ++k) {
    const float w = W2l[k];
    const float p0 = Pl[uu0][k], p1 = Pl[uu1][k];
    const float q0 = Ql[vv0][k], q1 = Ql[vv1][k];
    a00 = fmaf(fmaxf(p0 + q0, 0.f), w, a00);
    a01 = fmaf(fmaxf(p0 + q1, 0.f), w, a01);
    a10 = fmaf(fmaxf(p1 + q0, 0.f), w, a10);
    a11 = fmaf(fmaxf(p1 + q1, 0.f), w, a11);
  }
  const float bb = b2[0];
  const float s00 = 1.f / (1.f + __expf(-(a00 + bb)));
  const float s01 = 1.f / (1.f + __expf(-(a01 + bb)));
  const float s10 = 1.f / (1.f + __expf(-(a10 + bb)));
  const float s11 = 1.f / (1.f + __expf(-(a11 + bb)));
  float* SAb = SA + b * C_ * C_;
  SAb[(v0 + vv0) * C_ + (u0 + uu0)] = s00 * Aa[(u0 + uu0) * C_ + (v0 + vv0)];
  SAb[(v0 + vv1) * C_ + (u0 + uu0)] = s01 * Aa[(u0 + uu0) * C_ + (v0 + vv1)];
  SAb[(v0 + vv0) * C_ + (u0 + uu1)] = s10 * Aa[(u0 + uu1) * C_ + (v0 + vv0)];
  SAb[(v0 + vv1) * C_ + (u0 + uu1)] = s11 * Aa[(u0 + uu1) * C_ + (v0 + vv1)];
}

// K3: AT[b,v,d] = sum_u SA_T[b,v,u]*h[b,u,d]
//     MT[b,v,d] = (sum_u Am[u,v]*h[b,u,d]) * h[b,v,d]
__global__ __launch_bounds__(256) void k3_agg(const float* __restrict__ SA,
                                              const float* __restrict__ Am,
                                              const float* __restrict__ h,
                                              float* __restrict__ AT,
                                              float* __restrict__ MT) {
  const int b = blockIdx.y;
  const int v0 = blockIdx.x * 8;
  const int tid = threadIdx.x;  // d
  __shared__ float SAl[8][128];
  __shared__ float AmT[8][128];
  for (int i = tid; i < 8 * 128; i += 256) {
    const int r = i >> 7, u = i & 127;
    SAl[r][u] = SA[b * C_ * C_ + (v0 + r) * C_ + u];
    AmT[r][u] = Am[u * C_ + (v0 + r)];
  }
  __syncthreads();
  const float* hb = h + b * C_ * D_;
  float accA[8], accM[8];
#pragma unroll
  for (int r = 0; r < 8; ++r) { accA[r] = 0.f; accM[r] = 0.f; }
#pragma unroll 2
  for (int u = 0; u < C_; ++u) {
    const float hv = hb[u * D_ + tid];
#pragma unroll
    for (int r = 0; r < 8; ++r) {
      accA[r] = fmaf(SAl[r][u], hv, accA[r]);
      accM[r] = fmaf(AmT[r][u], hv, accM[r]);
    }
  }
#pragma unroll
  for (int r = 0; r < 8; ++r) {
    const float hvv = hb[(v0 + r) * D_ + tid];
    AT[(b * C_ + v0 + r) * D_ + tid] = accA[r];
    MT[(b * C_ + v0 + r) * D_ + tid] = accM[r] * hvv;
  }
}

// K4: z[row,e] = beta1*h + beta2*(sum_d AT[row,d]*Wa[d,e] + ba[e])
//                        + beta3*(sum_d MT[row,d]*Wm[d,e] + bm[e])
__global__ __launch_bounds__(256) void k4_out(const float* __restrict__ h,
                                              const float* __restrict__ AT,
                                              const float* __restrict__ MT,
                                              const float* __restrict__ Wa,
                                              const float* __restrict__ ba,
                                              const float* __restrict__ Wm,
                                              const float* __restrict__ bm,
                                              const float* __restrict__ be1,
                                              const float* __restrict__ be2,
                                              const float* __restrict__ be3,
                                              float* __restrict__ z) {
  const int tid = threadIdx.x;
  const int col = blockIdx.x * 128 + (tid & 127);
  const int rbase = (tid >> 7) * 8;
  const int row0 = blockIdx.y * 16;
  __shared__ float As[16][D_];
  __shared__ float Ms[16][D_];
#pragma unroll
  for (int r = 0; r < 16; ++r) {
    As[r][tid] = AT[(row0 + r) * D_ + tid];
    Ms[r][tid] = MT[(row0 + r) * D_ + tid];
  }
  __syncthreads();
  float accA[8], accM[8];
#pragma unroll
  for (int r = 0; r < 8; ++r) { accA[r] = 0.f; accM[r] = 0.f; }
#pragma unroll 4
  for (int d = 0; d < D_; ++d) {
    const float wa = Wa[d * D_ + col];
    const float wm = Wm[d * D_ + col];
#pragma unroll
    for (int r = 0; r < 8; ++r) {
      accA[r] = fmaf(As[rbase + r][d], wa, accA[r]);
      accM[r] = fmaf(Ms[rbase + r][d], wm, accM[r]);
    }
  }
  const float b1v = be1[0], b2v = be2[0], b3v = be3[0];
  const float bav = ba[col], bmv = bm[col];
#pragma unroll
  for (int r = 0; r < 8; ++r) {
    const int row = row0 + rbase + r;
    const float hv = h[row * D_ + col];
    z[row * D_ + col] = b1v * hv + b2v * (accA[r] + bav) + b3v * (accM[r] + bmv);
  }
}

extern "C" void kernel_launch(void* const* d_in, const int* in_sizes, int n_in,
                              void* d_out, int out_size, void* d_ws, size_t ws_size,
                              hipStream_t stream) {
  const float* h   = (const float*)d_in[0];
  const float* Aa  = (const float*)d_in[1];
  const float* Am  = (const float*)d_in[2];
  const float* W1  = (const float*)d_in[3];
  const float* b1  = (const float*)d_in[4];
  const float* W2  = (const float*)d_in[5];
  const float* b2  = (const float*)d_in[6];
  const float* Wa  = (const float*)d_in[7];
  const float* ba  = (const float*)d_in[8];
  const float* Wm  = (const float*)d_in[9];
  const float* bm  = (const float*)d_in[10];
  const float* be1 = (const float*)d_in[11];
  const float* be2 = (const float*)d_in[12];
  const float* be3 = (const float*)d_in[13];
  float* z = (float*)d_out;

  float* ws = (float*)d_ws;
  float* P  = ws;                       // B*C*D = 524288 floats
  float* Q  = P + (B_ * C_ * D_);       // 524288
  float* SA = Q + (B_ * C_ * D_);       // B*C*C = 262144 (stored transposed: [b][v][u])
  float* AT = SA + (B_ * C_ * C_);      // 524288
  float* MT = AT + (B_ * C_ * D_);      // 524288

  k1_pq <<<dim3(2, 128),   256, 0, stream>>>(h, W1, b1, P, Q);
  k2_s  <<<dim3(4, 4, 16), 256, 0, stream>>>(P, Q, W2, b2, Aa, SA);
  k3_agg<<<dim3(16, 16),   256, 0, stream>>>(SA, Am, h, AT, MT);
  k4_out<<<dim3(2, 128),   256, 0, stream>>>(h, AT, MT, Wa, ba, Wm, bm, be1, be2, be3, z);
}

// Round 3
// 142.772 us; speedup vs baseline: 1.6182x; 1.6182x over previous
//
#include <hip/hip_runtime.h>

#define B_ 16
#define C_ 128
#define D_ 256

// ---------------------------------------------------------------------------
// K1: P[row,k] = sum_d h[row,d]*W1[d,k];  Q[row,k] = sum_d h[row,d]*W1[D+d,k] + b1[k]
// row = b*C+u flat (2048 rows). Virtual col space 512: col<256 -> P, else Q.
// Block: 32 rows x 64 vcols, 256 thr = 64 cols x 4 rowgroups, 8 rows/thread.
// Grid (8, 64) = 512 blocks.
// ---------------------------------------------------------------------------
__global__ __launch_bounds__(256) void k1_pq(const float* __restrict__ h,
                                             const float* __restrict__ W1,
                                             const float* __restrict__ b1,
                                             float* __restrict__ P,
                                             float* __restrict__ Q) {
  const int tid = threadIdx.x;
  const int col = blockIdx.x * 64 + (tid & 63);   // 0..511
  const int rbase = (tid >> 6) * 8;               // 0,8,16,24
  const int row0 = blockIdx.y * 32;
  __shared__ float hs[32][D_];
#pragma unroll
  for (int r = 0; r < 32; ++r) hs[r][tid] = h[(row0 + r) * D_ + tid];
  __syncthreads();

  // column pointer into W1: Q-half starts at row 256 (offset 256*256)
  const int c = col & 255;
  const float* Wcol = W1 + c + ((col & 256) << 8);

  float acc[8];
#pragma unroll
  for (int i = 0; i < 8; ++i) acc[i] = 0.f;

#pragma unroll 2
  for (int d = 0; d < D_; d += 4) {
    const float w0 = Wcol[(d + 0) * D_];
    const float w1 = Wcol[(d + 1) * D_];
    const float w2 = Wcol[(d + 2) * D_];
    const float w3 = Wcol[(d + 3) * D_];
#pragma unroll
    for (int i = 0; i < 8; ++i) {
      const float4 hv = *(const float4*)&hs[rbase + i][d];
      acc[i] = fmaf(hv.x, w0, acc[i]);
      acc[i] = fmaf(hv.y, w1, acc[i]);
      acc[i] = fmaf(hv.z, w2, acc[i]);
      acc[i] = fmaf(hv.w, w3, acc[i]);
    }
  }

  if (col < 256) {
#pragma unroll
    for (int i = 0; i < 8; ++i) P[(row0 + rbase + i) * D_ + c] = acc[i];
  } else {
    const float bb = b1[c];
#pragma unroll
    for (int i = 0; i < 8; ++i) Q[(row0 + rbase + i) * D_ + c] = acc[i] + bb;
  }
}

// ---------------------------------------------------------------------------
// K2: SA_T[b,v,u] = sigmoid( sum_k relu(P[b,u,k]+Q[b,v,k])*W2[k] + b2 ) * Aa[u,v]
// 32x32 (u,v) tile / block, 2x2 per thread. P/Q tiles in LDS (stride 258 floats
// -> float2 reads are <=2-way bank aliased, free). W2 read as wave-uniform
// scalar loads from global (L2-hot).
// Grid (4,4,16) = 256 blocks.
// ---------------------------------------------------------------------------
__global__ __launch_bounds__(256) void k2_s(const float* __restrict__ P,
                                            const float* __restrict__ Q,
                                            const float* __restrict__ W2,
                                            const float* __restrict__ b2,
                                            const float* __restrict__ Aa,
                                            float* __restrict__ SA) {
  const int b = blockIdx.z;
  const int u0 = blockIdx.x * 32;
  const int v0 = blockIdx.y * 32;
  const int tid = threadIdx.x;
  const int tx = tid & 15;   // v pair
  const int ty = tid >> 4;   // u pair
  __shared__ float Pl[32][258];
  __shared__ float Ql[32][258];
  const float* Pb = P + (b * C_ + u0) * D_;
  const float* Qb = Q + (b * C_ + v0) * D_;
#pragma unroll
  for (int r = 0; r < 32; ++r) {
    Pl[r][tid] = Pb[r * D_ + tid];
    Ql[r][tid] = Qb[r * D_ + tid];
  }
  __syncthreads();

  const int uu0 = 2 * ty, uu1 = uu0 + 1;
  const int vv0 = 2 * tx, vv1 = vv0 + 1;
  const float2* __restrict__ pr0 = (const float2*)&Pl[uu0][0];
  const float2* __restrict__ pr1 = (const float2*)&Pl[uu1][0];
  const float2* __restrict__ qr0 = (const float2*)&Ql[vv0][0];
  const float2* __restrict__ qr1 = (const float2*)&Ql[vv1][0];
  const float2* __restrict__ w2v = (const float2*)W2;

  float a00 = 0.f, a01 = 0.f, a10 = 0.f, a11 = 0.f;
#pragma unroll 4
  for (int kk = 0; kk < D_ / 2; ++kk) {
    const float2 w = w2v[kk];            // wave-uniform -> s_load
    const float2 p0 = pr0[kk];
    const float2 p1 = pr1[kk];
    const float2 q0 = qr0[kk];
    const float2 q1 = qr1[kk];
    a00 = fmaf(fmaxf(p0.x + q0.x, 0.f), w.x, a00);
    a00 = fmaf(fmaxf(p0.y + q0.y, 0.f), w.y, a00);
    a01 = fmaf(fmaxf(p0.x + q1.x, 0.f), w.x, a01);
    a01 = fmaf(fmaxf(p0.y + q1.y, 0.f), w.y, a01);
    a10 = fmaf(fmaxf(p1.x + q0.x, 0.f), w.x, a10);
    a10 = fmaf(fmaxf(p1.y + q0.y, 0.f), w.y, a10);
    a11 = fmaf(fmaxf(p1.x + q1.x, 0.f), w.x, a11);
    a11 = fmaf(fmaxf(p1.y + q1.y, 0.f), w.y, a11);
  }
  const float bb = b2[0];
  const float s00 = 1.f / (1.f + __expf(-(a00 + bb)));
  const float s01 = 1.f / (1.f + __expf(-(a01 + bb)));
  const float s10 = 1.f / (1.f + __expf(-(a10 + bb)));
  const float s11 = 1.f / (1.f + __expf(-(a11 + bb)));
  float* SAb = SA + b * C_ * C_;
  SAb[(v0 + vv0) * C_ + (u0 + uu0)] = s00 * Aa[(u0 + uu0) * C_ + (v0 + vv0)];
  SAb[(v0 + vv1) * C_ + (u0 + uu0)] = s01 * Aa[(u0 + uu0) * C_ + (v0 + vv1)];
  SAb[(v0 + vv0) * C_ + (u0 + uu1)] = s10 * Aa[(u0 + uu1) * C_ + (v0 + vv0)];
  SAb[(v0 + vv1) * C_ + (u0 + uu1)] = s11 * Aa[(u0 + uu1) * C_ + (v0 + vv1)];
}

// ---------------------------------------------------------------------------
// K3: AT[b,v,d] = sum_u SA_T[b,v,u]*h[b,u,d];  MT[b,v,d]=(sum_u Am[u,v]*h[b,u,d])*h[b,v,d]
// Block: 4 v-rows x 256 d. Grid (32,16) = 512 blocks.
// ---------------------------------------------------------------------------
__global__ __launch_bounds__(256) void k3_agg(const float* __restrict__ SA,
                                              const float* __restrict__ Am,
                                              const float* __restrict__ h,
                                              float* __restrict__ AT,
                                              float* __restrict__ MT) {
  const int b = blockIdx.y;
  const int v0 = blockIdx.x * 4;
  const int tid = threadIdx.x;  // d
  __shared__ float SAl[4][128];
  __shared__ float AmT[4][128];
  for (int i = tid; i < 4 * 128; i += 256) {
    const int r = i >> 7, u = i & 127;
    SAl[r][u] = SA[b * C_ * C_ + (v0 + r) * C_ + u];
    AmT[r][u] = Am[u * C_ + (v0 + r)];
  }
  __syncthreads();
  const float* hb = h + b * C_ * D_;
  float accA[4], accM[4];
#pragma unroll
  for (int r = 0; r < 4; ++r) { accA[r] = 0.f; accM[r] = 0.f; }
#pragma unroll 4
  for (int u = 0; u < C_; ++u) {
    const float hv = hb[u * D_ + tid];
#pragma unroll
    for (int r = 0; r < 4; ++r) {
      accA[r] = fmaf(SAl[r][u], hv, accA[r]);
      accM[r] = fmaf(AmT[r][u], hv, accM[r]);
    }
  }
#pragma unroll
  for (int r = 0; r < 4; ++r) {
    const float hvv = hb[(v0 + r) * D_ + tid];
    AT[(b * C_ + v0 + r) * D_ + tid] = accA[r];
    MT[(b * C_ + v0 + r) * D_ + tid] = accM[r] * hvv;
  }
}

// ---------------------------------------------------------------------------
// K4: z = beta1*h + beta2*(AT@Wa + ba) + beta3*(MT@Wm + bm)
// Block: 16 rows x 64 cols, 4 rows/thread (A and M). Grid (4,128) = 512 blocks.
// ---------------------------------------------------------------------------
__global__ __launch_bounds__(256) void k4_out(const float* __restrict__ h,
                                              const float* __restrict__ AT,
                                              const float* __restrict__ MT,
                                              const float* __restrict__ Wa,
                                              const float* __restrict__ ba,
                                              const float* __restrict__ Wm,
                                              const float* __restrict__ bm,
                                              const float* __restrict__ be1,
                                              const float* __restrict__ be2,
                                              const float* __restrict__ be3,
                                              float* __restrict__ z) {
  const int tid = threadIdx.x;
  const int col = blockIdx.x * 64 + (tid & 63);
  const int rbase = (tid >> 6) * 4;     // 0,4,8,12
  const int row0 = blockIdx.y * 16;
  __shared__ float As[16][D_];
  __shared__ float Ms[16][D_];
#pragma unroll
  for (int r = 0; r < 16; ++r) {
    As[r][tid] = AT[(row0 + r) * D_ + tid];
    Ms[r][tid] = MT[(row0 + r) * D_ + tid];
  }
  __syncthreads();

  const float* WaC = Wa + col;
  const float* WmC = Wm + col;
  float accA[4], accM[4];
#pragma unroll
  for (int i = 0; i < 4; ++i) { accA[i] = 0.f; accM[i] = 0.f; }

#pragma unroll 2
  for (int d = 0; d < D_; d += 4) {
    const float wa0 = WaC[(d + 0) * D_];
    const float wa1 = WaC[(d + 1) * D_];
    const float wa2 = WaC[(d + 2) * D_];
    const float wa3 = WaC[(d + 3) * D_];
    const float wm0 = WmC[(d + 0) * D_];
    const float wm1 = WmC[(d + 1) * D_];
    const float wm2 = WmC[(d + 2) * D_];
    const float wm3 = WmC[(d + 3) * D_];
#pragma unroll
    for (int i = 0; i < 4; ++i) {
      const float4 av = *(const float4*)&As[rbase + i][d];
      const float4 mv = *(const float4*)&Ms[rbase + i][d];
      accA[i] = fmaf(av.x, wa0, accA[i]);
      accA[i] = fmaf(av.y, wa1, accA[i]);
      accA[i] = fmaf(av.z, wa2, accA[i]);
      accA[i] = fmaf(av.w, wa3, accA[i]);
      accM[i] = fmaf(mv.x, wm0, accM[i]);
      accM[i] = fmaf(mv.y, wm1, accM[i]);
      accM[i] = fmaf(mv.z, wm2, accM[i]);
      accM[i] = fmaf(mv.w, wm3, accM[i]);
    }
  }

  const float b1v = be1[0], b2v = be2[0], b3v = be3[0];
  const float bav = ba[col], bmv = bm[col];
#pragma unroll
  for (int i = 0; i < 4; ++i) {
    const int row = row0 + rbase + i;
    const float hv = h[row * D_ + col];
    z[row * D_ + col] = b1v * hv + b2v * (accA[i] + bav) + b3v * (accM[i] + bmv);
  }
}

extern "C" void kernel_launch(void* const* d_in, const int* in_sizes, int n_in,
                              void* d_out, int out_size, void* d_ws, size_t ws_size,
                              hipStream_t stream) {
  const float* h   = (const float*)d_in[0];
  const float* Aa  = (const float*)d_in[1];
  const float* Am  = (const float*)d_in[2];
  const float* W1  = (const float*)d_in[3];
  const float* b1  = (const float*)d_in[4];
  const float* W2  = (const float*)d_in[5];
  const float* b2  = (const float*)d_in[6];
  const float* Wa  = (const float*)d_in[7];
  const float* ba  = (const float*)d_in[8];
  const float* Wm  = (const float*)d_in[9];
  const float* bm  = (const float*)d_in[10];
  const float* be1 = (const float*)d_in[11];
  const float* be2 = (const float*)d_in[12];
  const float* be3 = (const float*)d_in[13];
  float* z = (float*)d_out;

  float* ws = (float*)d_ws;
  float* P  = ws;                       // 2048*256
  float* Q  = P + (B_ * C_ * D_);
  float* SA = Q + (B_ * C_ * D_);      // [b][v][u]
  float* AT = SA + (B_ * C_ * C_);
  float* MT = AT + (B_ * C_ * D_);

  k1_pq <<<dim3(8, 64),    256, 0, stream>>>(h, W1, b1, P, Q);
  k2_s  <<<dim3(4, 4, 16), 256, 0, stream>>>(P, Q, W2, b2, Aa, SA);
  k3_agg<<<dim3(32, 16),   256, 0, stream>>>(SA, Am, h, AT, MT);
  k4_out<<<dim3(4, 128),   256, 0, stream>>>(h, AT, MT, Wa, ba, Wm, bm, be1, be2, be3, z);
}